// Round 7
// baseline (599.454 us; speedup 1.0000x reference)
//
#include <hip/hip_runtime.h>
#include <hip/hip_bf16.h>
#include <stdint.h>
#include <math.h>

// TreeLSTM on MI355X — v14: fix v13's subtree register spill.
// v13 post-mortem: subtree (1024 thr = 16 waves) forces <=128 regs/wave;
// body needs ~180 -> spill -> 77MB scratch writes + L2 pollution -> 281MB
// B-refetch -> 316us. v14 subtree: 512 thr = 8 waves, each wave runs TWO cts
// sequentially (ct = wave + 8*cp); __launch_bounds__(512,2) -> 256-reg
// budget, no spill. Read phase computes both cps' gates into regs; one
// barrier pair per 32-row chunk (same in-place ordering v13 verified).
// B from L2-hot BtP with 2-deep prefetch. prep/leaf/lev9-7 unchanged.

typedef __bf16 bf16x8 __attribute__((ext_vector_type(8)));
typedef float  f32x4  __attribute__((ext_vector_type(4)));
typedef int    i32x4  __attribute__((ext_vector_type(4)));

__device__ __forceinline__ float sigf(float x) { return 1.f / (1.f + __expf(-x)); }
__device__ __forceinline__ float tanhfast(float x) {
    return 1.f - 2.f / (__expf(2.f * x) + 1.f);   // stable at |x| large
}

// blocks 0..255: xg4[(v*256+k)*4+g] = bW[g][k] + sum_i emb[v][i]*W[g][i][k]
// blocks 256..575: pack U into MFMA-fragment order BtP
__global__ void prep_kernel(const float* __restrict__ emb, const float* __restrict__ W,
                            const float* __restrict__ bW, const float* __restrict__ U,
                            float* __restrict__ xg4, __bf16* __restrict__ BtP) {
    if (blockIdx.x < 256) {
        int g = blockIdx.x >> 6, v = blockIdx.x & 63, k = threadIdx.x;
        __shared__ float e[256];
        e[k] = emb[v * 256 + k];
        __syncthreads();
        float s = bW[g * 256 + k];
        const float* Wg = W + g * 65536 + k;
#pragma unroll 4
        for (int i = 0; i < 256; i++) s += e[i] * Wg[i * 256];
        xg4[(v * 256 + k) * 4 + g] = s;
    } else {
        int t = (blockIdx.x - 256) * 256 + threadIdx.x;   // < 81920
        int g    = t >> 14;
        int r    = t & 16383;
        int ct   = r >> 10;
        int ks   = (r >> 6) & 15;
        int lane = t & 63;
        int lr = lane & 15, q = lane >> 4;
        int col = ct * 16 + lr;
        int kbase = ks * 32 + q * 8;
        bf16x8 v8;
#pragma unroll
        for (int e2 = 0; e2 < 8; e2++) {
            int k = kbase + e2;
            int s = k >> 8, kk = k & 255;
            v8[e2] = (__bf16)U[((g * 2 + s) * 256 + kk) * 256 + col];
        }
        *(bf16x8*)(BtP + (long)t * 8) = v8;
    }
}

__global__ void leaf_kernel(const int* __restrict__ ids, const float* __restrict__ xg4,
                            __bf16* __restrict__ h, __bf16* __restrict__ c) {
    int col = threadIdx.x;                 // 0..255
    int r0 = blockIdx.x * 32;              // 2048 blocks x 32 rows
    for (int r = r0; r < r0 + 32; r++) {
        int b = r >> 10, j = r & 1023;
        int id = ids[b * 2046 + 1022 + j];
        f32x4 xv = *(const f32x4*)(xg4 + (id * 256 + col) * 4);
        float ig = sigf(xv.y);
        float og = sigf(xv.z);
        float ug = tanhfast(xv.w);
        float cv = ig * ug;
        float hv = og * tanhfast(cv);
        h[r * 256 + col] = (__bf16)hv;
        c[r * 256 + col] = (__bf16)cv;
    }
}

// ===== big levels (9..7): v12b measured kernel, unchanged =====
__global__ __launch_bounds__(1024, 4) void level_kernel(
    const __bf16* __restrict__ A, const __bf16* __restrict__ Cprev,
    const __bf16* __restrict__ BtP, const float* __restrict__ xg4,
    const int* __restrict__ ids, __bf16* __restrict__ h_out,
    __bf16* __restrict__ c_out, float* __restrict__ rh_out,
    int lev, int M, int RG, int NB, int NB16) {
    __shared__ __bf16 Blds[5 * 16 * 512];     // 80 KB
    const int gid = blockIdx.x;
    int rgslot, ct;
    if (NB16) { rgslot = gid & 15; ct = gid >> 4; }   // XCD-affine: gid%8==rg%8
    else      { rgslot = gid % NB; ct = gid / NB; }
    const int tid  = threadIdx.x;
    const int wave = tid >> 6;
    const int lane = tid & 63;
    const int lr = lane & 15, q = lane >> 4;
    const int gcol = ct * 16 + lr;
    const int n = 1 << lev;

#pragma unroll
    for (int i = 0; i < 5; i++) {
        int cc = tid + i * 1024;
        int g = cc >> 10;
        int r = cc & 1023;
        *(i32x4*)(&Blds[g * 8192 + r * 8]) =
            *(const i32x4*)(BtP + (long)(g * 16 + ct) * 8192 + r * 8);
    }
    __syncthreads();

    int rg0 = rgslot;
    long wrow = (long)rg0 * 512 + wave * 32;
    const __bf16* Ap = A + (wrow + lr) * 512 + q * 8;   // + mt*8192 + s*32
    bf16x8 af[4][2];
    if (wrow < M) {
#pragma unroll
        for (int mt = 0; mt < 2; mt++) {
            af[0][mt] = *(const bf16x8*)(Ap + mt * 8192);
            af[1][mt] = *(const bf16x8*)(Ap + mt * 8192 + 32);
        }
    }

    for (int rg = rg0; rg < RG; rg += NB) {
        wrow = (long)rg * 512 + wave * 32;
        const bool active = (wrow < M);

        int rgn = rg + NB;
        long wrown = (rgn < RG) ? ((long)rgn * 512 + wave * 32) : wrow;
        const __bf16* Apn = A + (wrown + lr) * 512 + q * 8;

        int idv[2][4];
        __bf16 clv[2][4], crv[2][4];
        if (active) {
#pragma unroll
            for (int mt = 0; mt < 2; mt++)
#pragma unroll
                for (int v = 0; v < 4; v++) {
                    long grow = wrow + mt * 16 + q * 4 + v;
                    int b = (int)(grow >> lev);
                    int j = (int)(grow & (n - 1));
                    idv[mt][v] = ids[b * 2046 + (n - 2) + j];
                    clv[mt][v] = Cprev[grow * 512 + gcol];
                    crv[mt][v] = Cprev[grow * 512 + 256 + gcol];
                }
        }

        if (active) {
            f32x4 acc[5][2];
#pragma unroll
            for (int g2 = 0; g2 < 5; g2++)
#pragma unroll
                for (int mt = 0; mt < 2; mt++)
                    acc[g2][mt] = (f32x4){0.f, 0.f, 0.f, 0.f};

            bf16x8 bb[2][5];
#pragma unroll
            for (int g2 = 0; g2 < 5; g2++)
                bb[0][g2] = *(const bf16x8*)(&Blds[g2 * 8192 + lane * 8]);

#pragma unroll
            for (int s = 0; s < 16; s++) {
                {   // A: 2 ahead; wraps into NEXT rg's steps 0,1 at s=14,15.
                    int sp = s + 2;
                    const __bf16* P = (sp < 16) ? Ap : Apn;
                    int so = sp & 15;
#pragma unroll
                    for (int mt = 0; mt < 2; mt++)
                        af[sp & 3][mt] = *(const bf16x8*)(P + mt * 8192 + so * 32);
                }
                if (s + 1 < 16) {                  // B: 1 step ahead from LDS
#pragma unroll
                    for (int g2 = 0; g2 < 5; g2++)
                        bb[(s + 1) & 1][g2] =
                            *(const bf16x8*)(&Blds[g2 * 8192 + (s + 1) * 512 + lane * 8]);
                }
#pragma unroll
                for (int g2 = 0; g2 < 5; g2++)
#pragma unroll
                    for (int mt = 0; mt < 2; mt++)
                        acc[g2][mt] = __builtin_amdgcn_mfma_f32_16x16x32_bf16(
                            af[s & 3][mt], bb[s & 1][g2], acc[g2][mt], 0, 0, 0);
            }

#pragma unroll
            for (int mt = 0; mt < 2; mt++) {
#pragma unroll
                for (int v = 0; v < 4; v++) {
                    long grow = wrow + mt * 16 + q * 4 + v;
                    f32x4 xv = *(const f32x4*)(xg4 + (idv[mt][v] * 256 + gcol) * 4);
                    float fl = sigf(acc[0][mt][v] + xv.x);   // f_l,f_r share gate0
                    float fr = sigf(acc[1][mt][v] + xv.x);
                    float ig = sigf(acc[2][mt][v] + xv.y);
                    float og = sigf(acc[3][mt][v] + xv.z);
                    float ug = tanhfast(acc[4][mt][v] + xv.w);
                    float cv = ig * ug + fl * (float)clv[mt][v]
                                       + fr * (float)crv[mt][v];
                    float hv = og * tanhfast(cv);
                    h_out[grow * 256 + gcol] = (__bf16)hv;
                    c_out[grow * 256 + gcol] = (__bf16)cv;
                    if (rh_out) rh_out[grow * 256 + gcol] = hv;
                }
            }
        }
        Ap = Apn;
    }
}

// ===== small levels (6..1) + scores: one block per batch, 512 thr = 8 waves.
// Wave w handles cts {w, w+8} sequentially (cp=0,1). hbuf/cbuf: child h/c,
// 128x256 bf16, XOR-swizzled 16B granules: addr = (row*512+colb)^(((row>>1)&7)<<4).
// Per 32-row chunk: READ phase (both cps: K-loop from hbuf + L2-hot BtP,
// gates computed into regs) | barrier | WRITE phase (both cps) | barrier.
__global__ __launch_bounds__(512, 2) void subtree_kernel(
    const __bf16* __restrict__ Hin, const __bf16* __restrict__ Cin,
    const __bf16* __restrict__ BtP, const float* __restrict__ xg4,
    const int* __restrict__ ids, const float* __restrict__ Ws,
    const float* __restrict__ bs, float* __restrict__ out) {
    __shared__ __bf16 hbuf[128 * 256];   // 64 KB
    __shared__ __bf16 cbuf[128 * 256];   // 64 KB
    __shared__ float  rhl[512];          // 2 KB
    const int b    = blockIdx.x;
    const int tid  = threadIdx.x;
    const int wave = tid >> 6;           // 0..7
    const int lane = tid & 63;
    const int lr = lane & 15, q = lane >> 4;

    // ---- Stage lev-7 output (128 child rows) into hbuf/cbuf, swizzled. ----
#pragma unroll
    for (int i = 0; i < 8; i++) {
        int idx = tid + i * 512;             // 16B granule, 0..4095
        int row = idx >> 5;
        int colb = (idx & 31) * 16;
        int dst = (row * 512 + colb) ^ (((row >> 1) & 7) << 4);
        *(i32x4*)((char*)hbuf + dst) =
            *(const i32x4*)(Hin + (long)(b * 128 + row) * 256 + (idx & 31) * 8);
        *(i32x4*)((char*)cbuf + dst) =
            *(const i32x4*)(Cin + (long)(b * 128 + row) * 256 + (idx & 31) * 8);
    }
    __syncthreads();

    for (int lev = 6; lev >= 1; lev--) {
        const int n   = 1 << lev;            // parents this level (per batch)
        const int off = n - 2;
        const int nch = (n > 32) ? 2 : 1;
        for (int ch = 0; ch < nch; ch++) {
            const int rbase = ch * 32;
            float hv_st[2][2][4], cv_st[2][2][4];

            // ---------- READ PHASE: both ct passes ----------
#pragma unroll
            for (int cp = 0; cp < 2; cp++) {
                const int ct = wave + 8 * cp;
                const int gcol = ct * 16 + lr;

                int idv[2][4];
                float clv[2][4], crv[2][4];
#pragma unroll
                for (int mt = 0; mt < 2; mt++)
#pragma unroll
                    for (int v = 0; v < 4; v++) {
                        int j = rbase + mt * 16 + q * 4 + v;  // garbage j>=n: safe
                        idv[mt][v] = ids[b * 2046 + off + j];
                        int c0r = 2 * j, c1r = 2 * j + 1;
                        int a0 = (c0r * 512 + gcol * 2) ^ (((c0r >> 1) & 7) << 4);
                        int a1 = (c1r * 512 + gcol * 2) ^ (((c1r >> 1) & 7) << 4);
                        clv[mt][v] = (float)*(const __bf16*)((const char*)cbuf + a0);
                        crv[mt][v] = (float)*(const __bf16*)((const char*)cbuf + a1);
                    }

                f32x4 acc[5][2];
#pragma unroll
                for (int g2 = 0; g2 < 5; g2++)
#pragma unroll
                    for (int mt = 0; mt < 2; mt++)
                        acc[g2][mt] = (f32x4){0.f, 0.f, 0.f, 0.f};

                const __bf16* Bp = BtP + (long)ct * 8192;   // + g2*131072 + s*512
                bf16x8 bb[3][5];
#pragma unroll
                for (int g2 = 0; g2 < 5; g2++) {
                    bb[0][g2] = *(const bf16x8*)(Bp + (long)g2 * 131072 + lane * 8);
                    bb[1][g2] = *(const bf16x8*)(Bp + (long)g2 * 131072 + 512 + lane * 8);
                }

#pragma unroll
                for (int s = 0; s < 16; s++) {
                    if (s + 2 < 16) {               // B: 2 ahead from L2
#pragma unroll
                        for (int g2 = 0; g2 < 5; g2++)
                            bb[(s + 2) % 3][g2] = *(const bf16x8*)(
                                Bp + (long)g2 * 131072 + (s + 2) * 512 + lane * 8);
                    }
                    bf16x8 af[2];
#pragma unroll
                    for (int mt = 0; mt < 2; mt++) {
                        int j0 = rbase + mt * 16 + lr;      // A row (parent)
                        int crow = 2 * j0 + (s >> 3);       // child row
                        int ab = (crow * 512 + ((s & 7) * 64 + q * 16))
                                 ^ (((crow >> 1) & 7) << 4);
                        af[mt] = *(const bf16x8*)((const char*)hbuf + ab);
                    }
#pragma unroll
                    for (int g2 = 0; g2 < 5; g2++)
#pragma unroll
                        for (int mt = 0; mt < 2; mt++)
                            acc[g2][mt] = __builtin_amdgcn_mfma_f32_16x16x32_bf16(
                                af[mt], bb[s % 3][g2], acc[g2][mt], 0, 0, 0);
                }

                // gates -> regs (no LDS writes yet)
#pragma unroll
                for (int mt = 0; mt < 2; mt++)
#pragma unroll
                    for (int v = 0; v < 4; v++) {
                        f32x4 xv = *(const f32x4*)(xg4 + (idv[mt][v] * 256 + gcol) * 4);
                        float fl = sigf(acc[0][mt][v] + xv.x);
                        float fr = sigf(acc[1][mt][v] + xv.x);
                        float ig = sigf(acc[2][mt][v] + xv.y);
                        float og = sigf(acc[3][mt][v] + xv.z);
                        float ug = tanhfast(acc[4][mt][v] + xv.w);
                        float cv = ig * ug + fl * clv[mt][v] + fr * crv[mt][v];
                        hv_st[cp][mt][v] = og * tanhfast(cv);
                        cv_st[cp][mt][v] = cv;
                    }
            }
            __syncthreads();    // all reads of this chunk complete

            // ---------- WRITE PHASE: both ct passes ----------
#pragma unroll
            for (int cp = 0; cp < 2; cp++) {
                const int ct = wave + 8 * cp;
                const int gcol = ct * 16 + lr;
#pragma unroll
                for (int mt = 0; mt < 2; mt++)
#pragma unroll
                    for (int v = 0; v < 4; v++) {
                        int j = rbase + mt * 16 + q * 4 + v;
                        if (j < n) {
                            float hv = hv_st[cp][mt][v];
                            int dst = (j * 512 + gcol * 2) ^ (((j >> 1) & 7) << 4);
                            *(__bf16*)((char*)hbuf + dst) = (__bf16)hv;
                            if (lev > 1) *(__bf16*)((char*)cbuf + dst) =
                                (__bf16)cv_st[cp][mt][v];
                            if (lev == 1) {
                                out[192 + b * 512 + j * 256 + gcol] = hv;
                                rhl[j * 256 + gcol] = hv;
                            }
                        }
                    }
            }
            __syncthreads();    // writes visible before next chunk/level reads
        }
    }

    // ---- scores: 3 dots of rh (512) per batch. ----
    if (tid < 192) {
        int t = tid >> 6, ln = tid & 63;
        float s = 0.f;
        for (int i = ln; i < 512; i += 64) s += rhl[i] * Ws[i * 3 + t];
        for (int o = 32; o > 0; o >>= 1) s += __shfl_down(s, o);
        if (ln == 0) out[b * 3 + t] = s + bs[t];
    }
}

extern "C" void kernel_launch(void* const* d_in, const int* in_sizes, int n_in,
                              void* d_out, int out_size, void* d_ws, size_t ws_size,
                              hipStream_t stream) {
    const int*   ids = (const int*)  d_in[0];
    const float* emb = (const float*)d_in[1];
    const float* W   = (const float*)d_in[2];
    const float* bW  = (const float*)d_in[3];
    const float* U   = (const float*)d_in[4];
    const float* Ws  = (const float*)d_in[5];
    const float* bs  = (const float*)d_in[6];
    float* out = (float*)d_out;   // [0:192) scores, [192:) root_hidden (64x512)

    char* ws = (char*)d_ws;
    float*  xg4 = (float*)ws;                   //   262144 B : xg4[64][256][4]
    __bf16* BtP = (__bf16*)(ws + 262144);       //  1310720 B : packed B fragments
    __bf16* h0  = (__bf16*)(ws + 1572864);      // 33554432 B : h ping (leaf-sized)
    __bf16* c0  = (__bf16*)(ws + 35127296);     // 33554432 B
    __bf16* h1  = (__bf16*)(ws + 68681728);     // 16777216 B : h pong
    __bf16* c1  = (__bf16*)(ws + 85458944);     // 16777216 B   (total 102236160 B)

    prep_kernel<<<dim3(576), dim3(256), 0, stream>>>(emb, W, bW, U, xg4, BtP);
    leaf_kernel<<<dim3(2048), dim3(256), 0, stream>>>(ids, xg4, h0, c0);

    __bf16* hb[2] = {h0, h1};
    __bf16* cb[2] = {c0, c1};
    int cur = 0;
    for (int lev = 9; lev >= 7; lev--) {
        int M = 64 << lev;                      // B * 2^lev rows
        int RG = M >> 9;
        int NB = (RG < 16) ? RG : 16;
        level_kernel<<<dim3(16 * NB), dim3(1024), 0, stream>>>(
            hb[cur], cb[cur], BtP, xg4, ids, hb[1 - cur], cb[1 - cur], nullptr,
            lev, M, RG, NB, (NB == 16) ? 1 : 0);
        cur = 1 - cur;
    }
    // after lev7: h1/c1 hold lev-7 output (8192 rows = 64 batches x 128)
    subtree_kernel<<<dim3(64), dim3(512), 0, stream>>>(
        h1, c1, BtP, xg4, ids, Ws, bs, out);
}

// Round 8
// 580.310 us; speedup vs baseline: 1.0330x; 1.0330x over previous
//
#include <hip/hip_runtime.h>
#include <hip/hip_bf16.h>
#include <stdint.h>
#include <math.h>

// TreeLSTM on MI355X — v15: subtree redesigned to eliminate register spill.
// v13/v14 post-mortem: ~80MB scratch writes (spill) thrash L2 -> 573MB of
// B-reads that should be L2-hits fetch 295MB from HBM -> 340us. The spill
// came from held state: deferred write-phase arrays + f32 child-c + deep B
// buffers. v15 subtree: (1) h ping-pongs between two LDS regions (read region
// / write region alternate per level) -> no in-place hazard -> gates written
// IMMEDIATELY, no hv_st/cv_st; one barrier per level. (2) c double-buffered
// in GLOBAL (cgA/cgB carved from dead h0) -> no cbuf, bf16 child-c.
// (3) v12b-proven geometry: 16 waves x 1 ct, bb[2][5] 1-deep, afr 1-deep.
// Arch regs ~100 < 128 budget. prep/leaf/lev9-7 unchanged (measured).

typedef __bf16 bf16x8 __attribute__((ext_vector_type(8)));
typedef float  f32x4  __attribute__((ext_vector_type(4)));
typedef int    i32x4  __attribute__((ext_vector_type(4)));

__device__ __forceinline__ float sigf(float x) { return 1.f / (1.f + __expf(-x)); }
__device__ __forceinline__ float tanhfast(float x) {
    return 1.f - 2.f / (__expf(2.f * x) + 1.f);   // stable at |x| large
}

// blocks 0..255: xg4[(v*256+k)*4+g] = bW[g][k] + sum_i emb[v][i]*W[g][i][k]
// blocks 256..575: pack U into MFMA-fragment order BtP
__global__ void prep_kernel(const float* __restrict__ emb, const float* __restrict__ W,
                            const float* __restrict__ bW, const float* __restrict__ U,
                            float* __restrict__ xg4, __bf16* __restrict__ BtP) {
    if (blockIdx.x < 256) {
        int g = blockIdx.x >> 6, v = blockIdx.x & 63, k = threadIdx.x;
        __shared__ float e[256];
        e[k] = emb[v * 256 + k];
        __syncthreads();
        float s = bW[g * 256 + k];
        const float* Wg = W + g * 65536 + k;
#pragma unroll 4
        for (int i = 0; i < 256; i++) s += e[i] * Wg[i * 256];
        xg4[(v * 256 + k) * 4 + g] = s;
    } else {
        int t = (blockIdx.x - 256) * 256 + threadIdx.x;   // < 81920
        int g    = t >> 14;
        int r    = t & 16383;
        int ct   = r >> 10;
        int ks   = (r >> 6) & 15;
        int lane = t & 63;
        int lr = lane & 15, q = lane >> 4;
        int col = ct * 16 + lr;
        int kbase = ks * 32 + q * 8;
        bf16x8 v8;
#pragma unroll
        for (int e2 = 0; e2 < 8; e2++) {
            int k = kbase + e2;
            int s = k >> 8, kk = k & 255;
            v8[e2] = (__bf16)U[((g * 2 + s) * 256 + kk) * 256 + col];
        }
        *(bf16x8*)(BtP + (long)t * 8) = v8;
    }
}

__global__ void leaf_kernel(const int* __restrict__ ids, const float* __restrict__ xg4,
                            __bf16* __restrict__ h, __bf16* __restrict__ c) {
    int col = threadIdx.x;                 // 0..255
    int r0 = blockIdx.x * 32;              // 2048 blocks x 32 rows
    for (int r = r0; r < r0 + 32; r++) {
        int b = r >> 10, j = r & 1023;
        int id = ids[b * 2046 + 1022 + j];
        f32x4 xv = *(const f32x4*)(xg4 + (id * 256 + col) * 4);
        float ig = sigf(xv.y);
        float og = sigf(xv.z);
        float ug = tanhfast(xv.w);
        float cv = ig * ug;
        float hv = og * tanhfast(cv);
        h[r * 256 + col] = (__bf16)hv;
        c[r * 256 + col] = (__bf16)cv;
    }
}

// ===== big levels (9..7): v12b measured kernel, unchanged =====
__global__ __launch_bounds__(1024, 4) void level_kernel(
    const __bf16* __restrict__ A, const __bf16* __restrict__ Cprev,
    const __bf16* __restrict__ BtP, const float* __restrict__ xg4,
    const int* __restrict__ ids, __bf16* __restrict__ h_out,
    __bf16* __restrict__ c_out, float* __restrict__ rh_out,
    int lev, int M, int RG, int NB, int NB16) {
    __shared__ __bf16 Blds[5 * 16 * 512];     // 80 KB
    const int gid = blockIdx.x;
    int rgslot, ct;
    if (NB16) { rgslot = gid & 15; ct = gid >> 4; }   // XCD-affine: gid%8==rg%8
    else      { rgslot = gid % NB; ct = gid / NB; }
    const int tid  = threadIdx.x;
    const int wave = tid >> 6;
    const int lane = tid & 63;
    const int lr = lane & 15, q = lane >> 4;
    const int gcol = ct * 16 + lr;
    const int n = 1 << lev;

#pragma unroll
    for (int i = 0; i < 5; i++) {
        int cc = tid + i * 1024;
        int g = cc >> 10;
        int r = cc & 1023;
        *(i32x4*)(&Blds[g * 8192 + r * 8]) =
            *(const i32x4*)(BtP + (long)(g * 16 + ct) * 8192 + r * 8);
    }
    __syncthreads();

    int rg0 = rgslot;
    long wrow = (long)rg0 * 512 + wave * 32;
    const __bf16* Ap = A + (wrow + lr) * 512 + q * 8;   // + mt*8192 + s*32
    bf16x8 af[4][2];
    if (wrow < M) {
#pragma unroll
        for (int mt = 0; mt < 2; mt++) {
            af[0][mt] = *(const bf16x8*)(Ap + mt * 8192);
            af[1][mt] = *(const bf16x8*)(Ap + mt * 8192 + 32);
        }
    }

    for (int rg = rg0; rg < RG; rg += NB) {
        wrow = (long)rg * 512 + wave * 32;
        const bool active = (wrow < M);

        int rgn = rg + NB;
        long wrown = (rgn < RG) ? ((long)rgn * 512 + wave * 32) : wrow;
        const __bf16* Apn = A + (wrown + lr) * 512 + q * 8;

        int idv[2][4];
        __bf16 clv[2][4], crv[2][4];
        if (active) {
#pragma unroll
            for (int mt = 0; mt < 2; mt++)
#pragma unroll
                for (int v = 0; v < 4; v++) {
                    long grow = wrow + mt * 16 + q * 4 + v;
                    int b = (int)(grow >> lev);
                    int j = (int)(grow & (n - 1));
                    idv[mt][v] = ids[b * 2046 + (n - 2) + j];
                    clv[mt][v] = Cprev[grow * 512 + gcol];
                    crv[mt][v] = Cprev[grow * 512 + 256 + gcol];
                }
        }

        if (active) {
            f32x4 acc[5][2];
#pragma unroll
            for (int g2 = 0; g2 < 5; g2++)
#pragma unroll
                for (int mt = 0; mt < 2; mt++)
                    acc[g2][mt] = (f32x4){0.f, 0.f, 0.f, 0.f};

            bf16x8 bb[2][5];
#pragma unroll
            for (int g2 = 0; g2 < 5; g2++)
                bb[0][g2] = *(const bf16x8*)(&Blds[g2 * 8192 + lane * 8]);

#pragma unroll
            for (int s = 0; s < 16; s++) {
                {   // A: 2 ahead; wraps into NEXT rg's steps 0,1 at s=14,15.
                    int sp = s + 2;
                    const __bf16* P = (sp < 16) ? Ap : Apn;
                    int so = sp & 15;
#pragma unroll
                    for (int mt = 0; mt < 2; mt++)
                        af[sp & 3][mt] = *(const bf16x8*)(P + mt * 8192 + so * 32);
                }
                if (s + 1 < 16) {                  // B: 1 step ahead from LDS
#pragma unroll
                    for (int g2 = 0; g2 < 5; g2++)
                        bb[(s + 1) & 1][g2] =
                            *(const bf16x8*)(&Blds[g2 * 8192 + (s + 1) * 512 + lane * 8]);
                }
#pragma unroll
                for (int g2 = 0; g2 < 5; g2++)
#pragma unroll
                    for (int mt = 0; mt < 2; mt++)
                        acc[g2][mt] = __builtin_amdgcn_mfma_f32_16x16x32_bf16(
                            af[s & 3][mt], bb[s & 1][g2], acc[g2][mt], 0, 0, 0);
            }

#pragma unroll
            for (int mt = 0; mt < 2; mt++) {
#pragma unroll
                for (int v = 0; v < 4; v++) {
                    long grow = wrow + mt * 16 + q * 4 + v;
                    f32x4 xv = *(const f32x4*)(xg4 + (idv[mt][v] * 256 + gcol) * 4);
                    float fl = sigf(acc[0][mt][v] + xv.x);   // f_l,f_r share gate0
                    float fr = sigf(acc[1][mt][v] + xv.x);
                    float ig = sigf(acc[2][mt][v] + xv.y);
                    float og = sigf(acc[3][mt][v] + xv.z);
                    float ug = tanhfast(acc[4][mt][v] + xv.w);
                    float cv = ig * ug + fl * (float)clv[mt][v]
                                       + fr * (float)crv[mt][v];
                    float hv = og * tanhfast(cv);
                    h_out[grow * 256 + gcol] = (__bf16)hv;
                    c_out[grow * 256 + gcol] = (__bf16)cv;
                    if (rh_out) rh_out[grow * 256 + gcol] = hv;
                }
            }
        }
        Ap = Apn;
    }
}

// ===== small levels (6..1) + scores: one block per batch, 1024 thr = 16
// waves, wave = ct. hbuf: 192 rows x 256 bf16 (96 KB), swizzled 16B granules
// (addr = (row*512+colb) ^ (((row>>1)&7)<<4)). Levels ping-pong: lev p=(6-lev)&1
// reads rows [rb, rb+..), writes rows [wb, wb+n) with {rb,wb} = p?{128,0}:{0,128}.
// No in-place hazard -> gates written immediately, ONE barrier per level.
// c double-buffered in GLOBAL (cgA/cgB): write cg at lev L, read at L-1.
__global__ __launch_bounds__(1024, 4) void subtree_kernel(
    const __bf16* __restrict__ Hin, const __bf16* __restrict__ Cin,
    const __bf16* __restrict__ BtP, const float* __restrict__ xg4,
    const int* __restrict__ ids, const float* __restrict__ Ws,
    const float* __restrict__ bs, __bf16* __restrict__ cgA,
    __bf16* __restrict__ cgB, float* __restrict__ out) {
    __shared__ __bf16 hbuf[192 * 256];   // 96 KB
    __shared__ float  rhl[512];          // 2 KB
    const int b    = blockIdx.x;
    const int tid  = threadIdx.x;
    const int wave = tid >> 6;           // = ct, 0..15
    const int lane = tid & 63;
    const int lr = lane & 15, q = lane >> 4;
    const int ct   = wave;
    const int gcol = ct * 16 + lr;

    // ---- Stage lev-7 h (128 rows) into rows [0,128), swizzled. ----
#pragma unroll
    for (int i = 0; i < 4; i++) {
        int idx = tid + i * 1024;            // 16B granule, 0..4095
        int row = idx >> 5;
        int colb = (idx & 31) * 16;
        int dst = (row * 512 + colb) ^ (((row >> 1) & 7) << 4);
        *(i32x4*)((char*)hbuf + dst) =
            *(const i32x4*)(Hin + (long)(b * 128 + row) * 256 + (idx & 31) * 8);
    }
    __syncthreads();

    const __bf16* Bp = BtP + (long)ct * 8192;    // + g2*131072 + s*512 + lane*8

    for (int lev = 6; lev >= 1; lev--) {
        const int n   = 1 << lev;
        const int off = n - 2;
        const int p   = (6 - lev) & 1;
        const int rb  = p ? 128 : 0;
        const int wb  = p ? 0 : 128;
        const __bf16* cread = (lev == 6) ? (Cin + (long)b * 128 * 256)
                            : ((p ? cgA : cgB) + (long)b * 64 * 256);
        __bf16* cwrite = (p ? cgB : cgA) + (long)b * 64 * 256;
        const int nch = (lev == 6) ? 2 : 1;

        for (int ch = 0; ch < nch; ch++) {
            const int rbase = ch * 32;

            // ---- Preload ids + children c (global, hidden under K-loop). ----
            int idv[2][4];
            __bf16 clv[2][4], crv[2][4];
#pragma unroll
            for (int mt = 0; mt < 2; mt++)
#pragma unroll
                for (int v = 0; v < 4; v++) {
                    int j = rbase + mt * 16 + q * 4 + v;   // j>=n garbage: safe
                    idv[mt][v] = ids[b * 2046 + off + j];
                    clv[mt][v] = cread[(2 * j) * 256 + gcol];
                    crv[mt][v] = cread[(2 * j + 1) * 256 + gcol];
                }

            f32x4 acc[5][2];
#pragma unroll
            for (int g2 = 0; g2 < 5; g2++)
#pragma unroll
                for (int mt = 0; mt < 2; mt++)
                    acc[g2][mt] = (f32x4){0.f, 0.f, 0.f, 0.f};

            // B: 1-deep prefetch from L2-hot BtP.
            bf16x8 bb[2][5];
#pragma unroll
            for (int g2 = 0; g2 < 5; g2++)
                bb[0][g2] = *(const bf16x8*)(Bp + (long)g2 * 131072 + lane * 8);

            // A: 1-deep prefetch from LDS.
            bf16x8 afr[2][2];
#pragma unroll
            for (int mt = 0; mt < 2; mt++) {
                int j0  = rbase + mt * 16 + lr;
                int row = rb + 2 * j0;                  // s=0: child 0
                int ab  = (row * 512 + q * 16) ^ (((row >> 1) & 7) << 4);
                afr[0][mt] = *(const bf16x8*)((const char*)hbuf + ab);
            }

#pragma unroll
            for (int s = 0; s < 16; s++) {
                if (s + 1 < 16) {
#pragma unroll
                    for (int g2 = 0; g2 < 5; g2++)
                        bb[(s + 1) & 1][g2] = *(const bf16x8*)(
                            Bp + (long)g2 * 131072 + (s + 1) * 512 + lane * 8);
#pragma unroll
                    for (int mt = 0; mt < 2; mt++) {
                        int sp  = s + 1;
                        int j0  = rbase + mt * 16 + lr;
                        int row = rb + 2 * j0 + (sp >> 3);
                        int ab  = (row * 512 + ((sp & 7) * 64 + q * 16))
                                  ^ (((row >> 1) & 7) << 4);
                        afr[sp & 1][mt] = *(const bf16x8*)((const char*)hbuf + ab);
                    }
                }
#pragma unroll
                for (int g2 = 0; g2 < 5; g2++)
#pragma unroll
                    for (int mt = 0; mt < 2; mt++)
                        acc[g2][mt] = __builtin_amdgcn_mfma_f32_16x16x32_bf16(
                            afr[s & 1][mt], bb[s & 1][g2], acc[g2][mt], 0, 0, 0);
            }

            // ---- Epilogue: gates, write IMMEDIATELY (write region disjoint). --
#pragma unroll
            for (int mt = 0; mt < 2; mt++) {
#pragma unroll
                for (int v = 0; v < 4; v++) {
                    int j = rbase + mt * 16 + q * 4 + v;
                    if (j < n) {
                        f32x4 xv = *(const f32x4*)(xg4 + (idv[mt][v] * 256 + gcol) * 4);
                        float fl = sigf(acc[0][mt][v] + xv.x);
                        float fr = sigf(acc[1][mt][v] + xv.x);
                        float ig = sigf(acc[2][mt][v] + xv.y);
                        float og = sigf(acc[3][mt][v] + xv.z);
                        float ug = tanhfast(acc[4][mt][v] + xv.w);
                        float cv = ig * ug + fl * (float)clv[mt][v]
                                           + fr * (float)crv[mt][v];
                        float hv = og * tanhfast(cv);
                        int row = wb + j;
                        int dst = (row * 512 + gcol * 2) ^ (((row >> 1) & 7) << 4);
                        *(__bf16*)((char*)hbuf + dst) = (__bf16)hv;
                        if (lev > 1) cwrite[j * 256 + gcol] = (__bf16)cv;
                        if (lev == 1) {
                            out[192 + b * 512 + j * 256 + gcol] = hv;
                            rhl[j * 256 + gcol] = hv;
                        }
                    }
                }
            }
        }
        __syncthreads();    // level L writes visible before level L-1 reads
    }

    // ---- scores: 3 dots of rh (512) per batch. ----
    if (tid < 192) {
        int t = tid >> 6, ln = tid & 63;
        float s = 0.f;
        for (int i = ln; i < 512; i += 64) s += rhl[i] * Ws[i * 3 + t];
        for (int o = 32; o > 0; o >>= 1) s += __shfl_down(s, o);
        if (ln == 0) out[b * 3 + t] = s + bs[t];
    }
}

extern "C" void kernel_launch(void* const* d_in, const int* in_sizes, int n_in,
                              void* d_out, int out_size, void* d_ws, size_t ws_size,
                              hipStream_t stream) {
    const int*   ids = (const int*)  d_in[0];
    const float* emb = (const float*)d_in[1];
    const float* W   = (const float*)d_in[2];
    const float* bW  = (const float*)d_in[3];
    const float* U   = (const float*)d_in[4];
    const float* Ws  = (const float*)d_in[5];
    const float* bs  = (const float*)d_in[6];
    float* out = (float*)d_out;   // [0:192) scores, [192:) root_hidden (64x512)

    char* ws = (char*)d_ws;
    float*  xg4 = (float*)ws;                   //   262144 B : xg4[64][256][4]
    __bf16* BtP = (__bf16*)(ws + 262144);       //  1310720 B : packed B fragments
    __bf16* h0  = (__bf16*)(ws + 1572864);      // 33554432 B : h ping (leaf-sized)
    __bf16* c0  = (__bf16*)(ws + 35127296);     // 33554432 B
    __bf16* h1  = (__bf16*)(ws + 68681728);     // 16777216 B : h pong
    __bf16* c1  = (__bf16*)(ws + 85458944);     // 16777216 B   (total 102236160 B)
    // cgA/cgB (2MB each) carved from h0, which is DEAD after lev7 reads it.
    __bf16* cgA = h0;
    __bf16* cgB = h0 + 64 * 64 * 256;

    prep_kernel<<<dim3(576), dim3(256), 0, stream>>>(emb, W, bW, U, xg4, BtP);
    leaf_kernel<<<dim3(2048), dim3(256), 0, stream>>>(ids, xg4, h0, c0);

    __bf16* hb[2] = {h0, h1};
    __bf16* cb[2] = {c0, c1};
    int cur = 0;
    for (int lev = 9; lev >= 7; lev--) {
        int M = 64 << lev;                      // B * 2^lev rows
        int RG = M >> 9;
        int NB = (RG < 16) ? RG : 16;
        level_kernel<<<dim3(16 * NB), dim3(1024), 0, stream>>>(
            hb[cur], cb[cur], BtP, xg4, ids, hb[1 - cur], cb[1 - cur], nullptr,
            lev, M, RG, NB, (NB == 16) ? 1 : 0);
        cur = 1 - cur;
    }
    // after lev7: h1/c1 hold lev-7 output (8192 rows = 64 batches x 128)
    subtree_kernel<<<dim3(64), dim3(1024), 0, stream>>>(
        h1, c1, BtP, xg4, ids, Ws, bs, cgA, cgB, out);
}

// Round 9
// 561.171 us; speedup vs baseline: 1.0682x; 1.0341x over previous
//
#include <hip/hip_runtime.h>
#include <hip/hip_bf16.h>
#include <stdint.h>
#include <math.h>

// TreeLSTM on MI355X — v16: revert to v12b per-level structure (415.7us
// verified) after the subtree fusion dead-end (v13/14/15: identical 282MB
// FETCH across 3 register plans -> structural B-traffic, not spill; per-batch
// blocks re-stream the 1.25MB BtP 7x each = 573MB demand on 64 CUs).
// Changes vs v12b:
//  (1) prep fused (xg+bt, verified in v13-15)           -> -1 dispatch
//  (2) lev-loop A-prefetch 2-deep -> 3-deep lookahead   -> zero extra VGPR
//      (af[4][2] already has 4 slots; 375cy x 4-wave TLP covers ~900cy HBM)
//  (3) s_setprio(1) around the MFMA cluster (free-running waves = the
//      regime where it measured +4-7%)

typedef __bf16 bf16x8 __attribute__((ext_vector_type(8)));
typedef float  f32x4  __attribute__((ext_vector_type(4)));
typedef int    i32x4  __attribute__((ext_vector_type(4)));

__device__ __forceinline__ float sigf(float x) { return 1.f / (1.f + __expf(-x)); }
__device__ __forceinline__ float tanhfast(float x) {
    return 1.f - 2.f / (__expf(2.f * x) + 1.f);   // stable at |x| large
}

// blocks 0..255: xg4[(v*256+k)*4+g] = bW[g][k] + sum_i emb[v][i]*W[g][i][k]
// blocks 256..575: pack U into MFMA-fragment order BtP
__global__ void prep_kernel(const float* __restrict__ emb, const float* __restrict__ W,
                            const float* __restrict__ bW, const float* __restrict__ U,
                            float* __restrict__ xg4, __bf16* __restrict__ BtP) {
    if (blockIdx.x < 256) {
        int g = blockIdx.x >> 6, v = blockIdx.x & 63, k = threadIdx.x;
        __shared__ float e[256];
        e[k] = emb[v * 256 + k];
        __syncthreads();
        float s = bW[g * 256 + k];
        const float* Wg = W + g * 65536 + k;
#pragma unroll 4
        for (int i = 0; i < 256; i++) s += e[i] * Wg[i * 256];
        xg4[(v * 256 + k) * 4 + g] = s;
    } else {
        int t = (blockIdx.x - 256) * 256 + threadIdx.x;   // < 81920
        int g    = t >> 14;
        int r    = t & 16383;
        int ct   = r >> 10;
        int ks   = (r >> 6) & 15;
        int lane = t & 63;
        int lr = lane & 15, q = lane >> 4;
        int col = ct * 16 + lr;
        int kbase = ks * 32 + q * 8;
        bf16x8 v8;
#pragma unroll
        for (int e2 = 0; e2 < 8; e2++) {
            int k = kbase + e2;
            int s = k >> 8, kk = k & 255;
            v8[e2] = (__bf16)U[((g * 2 + s) * 256 + kk) * 256 + col];
        }
        *(bf16x8*)(BtP + (long)t * 8) = v8;
    }
}

__global__ void leaf_kernel(const int* __restrict__ ids, const float* __restrict__ xg4,
                            __bf16* __restrict__ h, __bf16* __restrict__ c) {
    int col = threadIdx.x;                 // 0..255
    int r0 = blockIdx.x * 32;              // 2048 blocks x 32 rows
    for (int r = r0; r < r0 + 32; r++) {
        int b = r >> 10, j = r & 1023;
        int id = ids[b * 2046 + 1022 + j];
        f32x4 xv = *(const f32x4*)(xg4 + (id * 256 + col) * 4);
        float ig = sigf(xv.y);
        float og = sigf(xv.z);
        float ug = tanhfast(xv.w);
        float cv = ig * ug;
        float hv = og * tanhfast(cv);
        h[r * 256 + col] = (__bf16)hv;
        c[r * 256 + col] = (__bf16)cv;
    }
}

// Block = 1024 thr = 16 waves x 32 rows; one ct (16 cols), all 5 gates.
// Grid = 16*NB blocks. NB16=1 -> rgslot = gid&15, ct = gid>>4.
__global__ __launch_bounds__(1024, 4) void level_kernel(
    const __bf16* __restrict__ A, const __bf16* __restrict__ Cprev,
    const __bf16* __restrict__ BtP, const float* __restrict__ xg4,
    const int* __restrict__ ids, __bf16* __restrict__ h_out,
    __bf16* __restrict__ c_out, float* __restrict__ rh_out,
    int lev, int M, int RG, int NB, int NB16) {
    __shared__ __bf16 Blds[5 * 16 * 512];     // 80 KB
    const int gid = blockIdx.x;
    int rgslot, ct;
    if (NB16) { rgslot = gid & 15; ct = gid >> 4; }   // XCD-affine: gid%8==rg%8
    else      { rgslot = gid % NB; ct = gid / NB; }
    const int tid  = threadIdx.x;
    const int wave = tid >> 6;
    const int lane = tid & 63;
    const int lr = lane & 15, q = lane >> 4;
    const int gcol = ct * 16 + lr;
    const int n = 1 << lev;

    // ---- Stage B-slice -> LDS ONCE per block (fragment order, 16B/lane). ----
#pragma unroll
    for (int i = 0; i < 5; i++) {
        int cc = tid + i * 1024;
        int g = cc >> 10;
        int r = cc & 1023;
        *(i32x4*)(&Blds[g * 8192 + r * 8]) =
            *(const i32x4*)(BtP + (long)(g * 16 + ct) * 8192 + r * 8);
    }
    __syncthreads();

    // ---- First rg: prologue A prefetch into slots 0,1,2 (3-deep). ----
    int rg0 = rgslot;
    long wrow = (long)rg0 * 512 + wave * 32;
    const __bf16* Ap = A + (wrow + lr) * 512 + q * 8;   // + mt*8192 + s*32
    bf16x8 af[4][2];
    if (wrow < M) {
#pragma unroll
        for (int mt = 0; mt < 2; mt++) {
            af[0][mt] = *(const bf16x8*)(Ap + mt * 8192);
            af[1][mt] = *(const bf16x8*)(Ap + mt * 8192 + 32);
            af[2][mt] = *(const bf16x8*)(Ap + mt * 8192 + 64);
        }
    }

    for (int rg = rg0; rg < RG; rg += NB) {
        wrow = (long)rg * 512 + wave * 32;
        const bool active = (wrow < M);

        // Next rg's A base (wrap to current on last rg -> harmless re-reads).
        int rgn = rg + NB;
        long wrown = (rgn < RG) ? ((long)rgn * 512 + wave * 32) : wrow;
        const __bf16* Apn = A + (wrown + lr) * 512 + q * 8;

        // ---- Preload ids + children's c (latency hides under the K-loop). --
        int idv[2][4];
        __bf16 clv[2][4], crv[2][4];
        if (active) {
#pragma unroll
            for (int mt = 0; mt < 2; mt++)
#pragma unroll
                for (int v = 0; v < 4; v++) {
                    long grow = wrow + mt * 16 + q * 4 + v;
                    int b = (int)(grow >> lev);
                    int j = (int)(grow & (n - 1));
                    idv[mt][v] = ids[b * 2046 + (n - 2) + j];
                    clv[mt][v] = Cprev[grow * 512 + gcol];
                    crv[mt][v] = Cprev[grow * 512 + 256 + gcol];
                }
        }

        if (active) {
            f32x4 acc[5][2];
#pragma unroll
            for (int g2 = 0; g2 < 5; g2++)
#pragma unroll
                for (int mt = 0; mt < 2; mt++)
                    acc[g2][mt] = (f32x4){0.f, 0.f, 0.f, 0.f};

            bf16x8 bb[2][5];
#pragma unroll
            for (int g2 = 0; g2 < 5; g2++)
                bb[0][g2] = *(const bf16x8*)(&Blds[g2 * 8192 + lane * 8]);

#pragma unroll
            for (int s = 0; s < 16; s++) {
                {   // A: 3 ahead; wraps into NEXT rg's steps 0..2 at s>=13.
                    int sp = s + 3;
                    const __bf16* P = (sp < 16) ? Ap : Apn;
                    int so = sp & 15;
#pragma unroll
                    for (int mt = 0; mt < 2; mt++)
                        af[sp & 3][mt] = *(const bf16x8*)(P + mt * 8192 + so * 32);
                }
                if (s + 1 < 16) {                  // B: 1 step ahead from LDS
#pragma unroll
                    for (int g2 = 0; g2 < 5; g2++)
                        bb[(s + 1) & 1][g2] =
                            *(const bf16x8*)(&Blds[g2 * 8192 + (s + 1) * 512 + lane * 8]);
                }
                __builtin_amdgcn_s_setprio(1);
#pragma unroll
                for (int g2 = 0; g2 < 5; g2++)
#pragma unroll
                    for (int mt = 0; mt < 2; mt++)
                        acc[g2][mt] = __builtin_amdgcn_mfma_f32_16x16x32_bf16(
                            af[s & 3][mt], bb[s & 1][g2], acc[g2][mt], 0, 0, 0);
                __builtin_amdgcn_s_setprio(0);
            }

            // ---- Epilogue: gate combine. col=lane&15, row=q*4+v. ----
#pragma unroll
            for (int mt = 0; mt < 2; mt++) {
#pragma unroll
                for (int v = 0; v < 4; v++) {
                    long grow = wrow + mt * 16 + q * 4 + v;
                    f32x4 xv = *(const f32x4*)(xg4 + (idv[mt][v] * 256 + gcol) * 4);
                    float fl = sigf(acc[0][mt][v] + xv.x);   // f_l,f_r share gate0
                    float fr = sigf(acc[1][mt][v] + xv.x);
                    float ig = sigf(acc[2][mt][v] + xv.y);
                    float og = sigf(acc[3][mt][v] + xv.z);
                    float ug = tanhfast(acc[4][mt][v] + xv.w);
                    float cv = ig * ug + fl * (float)clv[mt][v]
                                       + fr * (float)crv[mt][v];
                    float hv = og * tanhfast(cv);
                    h_out[grow * 256 + gcol] = (__bf16)hv;
                    c_out[grow * 256 + gcol] = (__bf16)cv;
                    if (rh_out) rh_out[grow * 256 + gcol] = hv;
                }
            }
        }
        Ap = Apn;
    }
}

__global__ void scores_kernel(const float* __restrict__ rh, const float* __restrict__ Ws,
                              const float* __restrict__ bs, float* __restrict__ out) {
    int b = blockIdx.x;
    int t = threadIdx.x >> 6, lane = threadIdx.x & 63;
    float s = 0.f;
    for (int i = lane; i < 512; i += 64) s += rh[b * 512 + i] * Ws[i * 3 + t];
    for (int o = 32; o > 0; o >>= 1) s += __shfl_down(s, o);
    if (lane == 0) out[b * 3 + t] = s + bs[t];
}

extern "C" void kernel_launch(void* const* d_in, const int* in_sizes, int n_in,
                              void* d_out, int out_size, void* d_ws, size_t ws_size,
                              hipStream_t stream) {
    const int*   ids = (const int*)  d_in[0];
    const float* emb = (const float*)d_in[1];
    const float* W   = (const float*)d_in[2];
    const float* bW  = (const float*)d_in[3];
    const float* U   = (const float*)d_in[4];
    const float* Ws  = (const float*)d_in[5];
    const float* bs  = (const float*)d_in[6];
    float* out = (float*)d_out;   // [0:192) scores, [192:) root_hidden (64x512)

    char* ws = (char*)d_ws;
    float*  xg4 = (float*)ws;                   //   262144 B : xg4[64][256][4]
    __bf16* BtP = (__bf16*)(ws + 262144);       //  1310720 B : packed B fragments
    __bf16* h0  = (__bf16*)(ws + 1572864);      // 33554432 B : h ping (leaf-sized)
    __bf16* c0  = (__bf16*)(ws + 35127296);     // 33554432 B
    __bf16* h1  = (__bf16*)(ws + 68681728);     // 16777216 B : h pong
    __bf16* c1  = (__bf16*)(ws + 85458944);     // 16777216 B   (total 102236160 B)

    prep_kernel<<<dim3(576), dim3(256), 0, stream>>>(emb, W, bW, U, xg4, BtP);
    leaf_kernel<<<dim3(2048), dim3(256), 0, stream>>>(ids, xg4, h0, c0);

    __bf16* hb[2] = {h0, h1};
    __bf16* cb[2] = {c0, c1};
    int cur = 0;
    for (int lev = 9; lev >= 1; lev--) {
        int M = 64 << lev;                      // B * 2^lev rows
        int RG = M >> 9; if (RG < 1) RG = 1;
        int NB = (RG < 16) ? RG : 16;
        float* rh = (lev == 1) ? (out + 192) : nullptr;
        level_kernel<<<dim3(16 * NB), dim3(1024), 0, stream>>>(
            hb[cur], cb[cur], BtP, xg4, ids, hb[1 - cur], cb[1 - cur], rh,
            lev, M, RG, NB, (NB == 16) ? 1 : 0);
        cur = 1 - cur;
    }
    scores_kernel<<<dim3(64), dim3(192), 0, stream>>>(out + 192, Ws, bs, out);
}